// Round 5
// baseline (259.988 us; speedup 1.0000x reference)
//
#include <hip/hip_runtime.h>
#include <math.h>

// LSQ quantizer with Hadamard rotation via FWHT:
//   out_row = FWHT( h0 .* s .* rint(clamp(FWHT(x_row) .* h0 / s, -Qn, Qp)) )
// with h0 = hadamard[0,:] = signs/sqrt(D).
//
// Round-6: keep round-5's structure (2 LDS transposes + compile-time-variant
// permlane butterflies behind a one-shot probe), add 2-ROWS-PER-WAVE software
// pipelining on a SINGLE shared 8 KiB wave-private LDS buffer: every DS batch
// (8 x b128) is issued, then the OTHER row's next VALU stage runs before the
// lgkmcnt(0) drain, so all LDS latency is covered in-wave. LDS/block stays
// 32 KiB (5 blocks/CU); ILP per wave doubles.
//
// Bit partition of element index j (11 bits):
//   layout A: comps=j[0:2], lanes=j[2:8] (lane bit k = j[k+2]), regs=j[8:11]
//             -> VALU: comps {0,1}, regs {8,9,10}, perm16 = j6, perm32 = j7
//   layout B: comps=j[0:2], regs=j[2:5], lanes: bit5=j5, bits0..4=j[6:11]
//             -> VALU: regs {2,3,4}, perm32 = j5
// LDS swizzle on the linear float address a: a ^= ((a>>6)&7)<<2.
// (measured r3/r4: SQ_LDS_BANK_CONFLICT 8.9M -> 0.52M with this scheme)

constexpr int D  = 2048;
constexpr int NR = 8;   // float4 regs per lane: 8 * 4 * 64 = 2048

#define LGKM0() __asm__ __volatile__("s_waitcnt lgkmcnt(0)" ::: "memory")

typedef unsigned uint2v __attribute__((ext_vector_type(2)));
typedef float    f4v    __attribute__((ext_vector_type(4)));

__device__ __forceinline__ void bfly(float4& a, float4& b) {
    float4 ta = a, tb = b;
    a.x = ta.x + tb.x; a.y = ta.y + tb.y; a.z = ta.z + tb.z; a.w = ta.w + tb.w;
    b.x = ta.x - tb.x; b.y = ta.y - tb.y; b.z = ta.z - tb.z; b.w = ta.w - tb.w;
}

__device__ __forceinline__ void reg_stages(float4 (&v)[NR]) {
    #pragma unroll
    for (int m = 1; m <= 4; m <<= 1) {
        #pragma unroll
        for (int r = 0; r < NR; ++r)
            if ((r & m) == 0) bfly(v[r], v[r | m]);
    }
}

__device__ __forceinline__ void comp_stages(float4 (&v)[NR]) {
    #pragma unroll
    for (int r = 0; r < NR; ++r) {
        float a, b;
        a = v[r].x; b = v[r].y; v[r].x = a + b; v[r].y = a - b;   // bit 0
        a = v[r].z; b = v[r].w; v[r].z = a + b; v[r].w = a - b;
        a = v[r].x; b = v[r].z; v[r].x = a + b; v[r].z = a - b;   // bit 1
        a = v[r].y; b = v[r].w; v[r].y = a + b; v[r].w = a - b;
    }
}

// ---- raw permlane swaps (semantics probed at runtime, once) ----
__device__ __forceinline__ void plswap32(float& x, float& y) {
#if __has_builtin(__builtin_amdgcn_permlane32_swap)
    uint2v t = __builtin_amdgcn_permlane32_swap(
        __builtin_bit_cast(unsigned, x), __builtin_bit_cast(unsigned, y),
        false, false);
    x = __builtin_bit_cast(float, t[0]);
    y = __builtin_bit_cast(float, t[1]);
#else
    asm volatile("v_permlane32_swap_b32 %0, %1" : "+v"(x), "+v"(y));
#endif
}
__device__ __forceinline__ void plswap16(float& x, float& y) {
#if __has_builtin(__builtin_amdgcn_permlane16_swap)
    uint2v t = __builtin_amdgcn_permlane16_swap(
        __builtin_bit_cast(unsigned, x), __builtin_bit_cast(unsigned, y),
        false, false);
    x = __builtin_bit_cast(float, t[0]);
    y = __builtin_bit_cast(float, t[1]);
#else
    asm volatile("v_permlane16_swap_b32 %0, %1" : "+v"(x), "+v"(y));
#endif
}

// Probe: classify swap semantics into variant 0..3 (4 = unknown).
//   0: a <- [a_lo,b_lo], b <- [a_hi,b_hi]   (per m-group pair)
//   1: a <- [a_hi,b_hi], b <- [a_lo,b_lo]
//   2: a <- [b_hi,a_hi], b <- [b_lo,a_lo]
//   3: a <- [b_lo,a_lo], b <- [b_hi,a_hi]
template<bool IS32>
__device__ __forceinline__ int probe_var(int lane) {
    const int m = IS32 ? 32 : 16;
    float a = (float)lane, b = 1000.0f + (float)lane;
    if (IS32) plswap32(a, b); else plswap16(a, b);
    const bool hi = (lane & m) != 0;
    const float ea0 = hi ? 1000.0f + (float)(lane - m) : (float)lane;
    const float eb0 = hi ? 1000.0f + (float)lane       : (float)(lane + m);
    const float ea2 = hi ? (float)lane                 : 1000.0f + (float)(lane + m);
    const float eb2 = hi ? (float)(lane - m)           : 1000.0f + (float)lane;
    if (__all(a == ea0 && b == eb0)) return 0;
    if (__all(a == eb0 && b == ea0)) return 1;
    if (__all(a == ea2 && b == eb2)) return 2;
    if (__all(a == eb2 && b == ea2)) return 3;
    return 4;
}

// Lane butterfly on group-bit m for TWO registers at once, per variant.
// Final a=[sum_a,diff_a], b=[sum_b,diff_b] (diff = lo-hi). Verified per-variant.
template<int VAR, bool IS32>
__device__ __forceinline__ void bfly_l(float& a, float& b) {
    if (IS32) plswap32(a, b); else plswap16(a, b);
    float s = a + b;
    float d = (VAR == 0 || VAR == 3) ? (a - b) : (b - a);
    if (VAR == 0)      { if (IS32) plswap32(s, d); else plswap16(s, d); a = s; b = d; }
    else if (VAR == 1) { if (IS32) plswap32(s, d); else plswap16(s, d); a = d; b = s; }
    else if (VAR == 2) { if (IS32) plswap32(d, s); else plswap16(d, s); a = d; b = s; }
    else               { if (IS32) plswap32(d, s); else plswap16(d, s); a = s; b = d; }
}

// Known-correct fallback: xor-m butterfly via shuffle.
__device__ __forceinline__ void shfl_stage(float4 (&v)[NR], int m, int lane) {
    const bool hi = (lane & m) != 0;
    #pragma unroll
    for (int r = 0; r < NR; ++r) {
        float t;
        t = __shfl_xor(v[r].x, m); v[r].x = hi ? t - v[r].x : v[r].x + t;
        t = __shfl_xor(v[r].y, m); v[r].y = hi ? t - v[r].y : v[r].y + t;
        t = __shfl_xor(v[r].z, m); v[r].z = hi ? t - v[r].z : v[r].z + t;
        t = __shfl_xor(v[r].w, m); v[r].w = hi ? t - v[r].w : v[r].w + t;
    }
}

template<int VAR, bool IS32>
__device__ __forceinline__ void perm_stage(float4 (&v)[NR], int lane) {
    if constexpr (VAR == 4) {
        shfl_stage(v, IS32 ? 32 : 16, lane);
    } else {
        #pragma unroll
        for (int r = 0; r < NR; r += 2) {
            bfly_l<VAR, IS32>(v[r].x, v[r + 1].x);
            bfly_l<VAR, IS32>(v[r].y, v[r + 1].y);
            bfly_l<VAR, IS32>(v[r].z, v[r + 1].z);
            bfly_l<VAR, IS32>(v[r].w, v[r + 1].w);
        }
    }
}

__device__ __forceinline__ float quant1(float xh, float h0, float s, float inv_s,
                                        float nqn, float qp) {
    float u = xh * h0 * inv_s;
    u = fminf(fmaxf(u, nqn), qp);
    float q = rintf(u);                       // round half-to-even (jnp.round)
    return q * (s * h0);                      // *s, fold the second h0 multiply
}

__device__ __forceinline__ void quant_all(float4 (&v)[NR], const float4 (&h)[NR],
                                          float s, float inv_s, float nqn, float qp) {
    #pragma unroll
    for (int r = 0; r < NR; ++r) {
        v[r].x = quant1(v[r].x, h[r].x, s, inv_s, nqn, qp);
        v[r].y = quant1(v[r].y, h[r].y, s, inv_s, nqn, qp);
        v[r].z = quant1(v[r].z, h[r].z, s, inv_s, nqn, qp);
        v[r].w = quant1(v[r].w, h[r].w, s, inv_s, nqn, qp);
    }
}

// ---- FWHT stage groups (each j-bit butterflied exactly once per FWHT) ----
template<int VAR>
__device__ __forceinline__ void p1a(float4 (&v)[NR]) {           // bits 0,1,8,9,10
    comp_stages(v); reg_stages(v);
}
template<int VAR>
__device__ __forceinline__ void p1b(float4 (&v)[NR], int lane) { // bits 6,7
    perm_stage<VAR, false>(v, lane); perm_stage<VAR, true>(v, lane);
}
template<int VAR>
__device__ __forceinline__ void p2(float4 (&v)[NR], int lane) {  // bits 2,3,4,5
    reg_stages(v); perm_stage<VAR, true>(v, lane);
}
template<int VAR>
__device__ __forceinline__ void p4(float4 (&v)[NR], int lane) {  // bits 8,9,10,6,7,0,1
    reg_stages(v);
    perm_stage<VAR, false>(v, lane); perm_stage<VAR, true>(v, lane);
    comp_stages(v);
}

// ---- LDS transpose batches (8 x b128 each; swizzle a ^= ((a>>6)&7)<<2) ----
__device__ __forceinline__ void wAB(float* lds, const float4 (&v)[NR], int wA0) {
    #pragma unroll
    for (int r = 0; r < NR; ++r)
        *reinterpret_cast<float4*>(lds + (r << 8) + (wA0 ^ ((r & 1) << 4))) = v[r];
}
__device__ __forceinline__ void rAB(float* lds, float4 (&v)[NR], int rB0, int l7s) {
    #pragma unroll
    for (int q = 0; q < NR; ++q)
        v[q] = *reinterpret_cast<const float4*>(lds + rB0 + ((q << 2) ^ l7s));
}
__device__ __forceinline__ void wBA(float* lds, const float4 (&v)[NR], int rB0, int l7s) {
    #pragma unroll
    for (int q = 0; q < NR; ++q)
        *reinterpret_cast<float4*>(lds + rB0 + ((q << 2) ^ l7s)) = v[q];
}
__device__ __forceinline__ void rBA(float* lds, float4 (&v)[NR], int wA0) {
    #pragma unroll
    for (int r = 0; r < NR; ++r)
        v[r] = *reinterpret_cast<const float4*>(lds + (r << 8) + (wA0 ^ ((r & 1) << 4)));
}

// Two rows per wave, software-pipelined on one shared LDS buffer.
template<int VAR>
__device__ __forceinline__ void fwht_body(
    const float* __restrict__ x, const float* __restrict__ hadamard,
    float* __restrict__ out, float* lds, int lane, int rowA, int rowB, bool doB,
    float s, float inv_s, float nqn, float qp)
{
    float4 vA[NR], vB[NR], h[NR];
    {
        const float4* xa4 = reinterpret_cast<const float4*>(x + (size_t)rowA * D) + lane;
        const float4* xb4 = reinterpret_cast<const float4*>(x + (size_t)rowB * D) + lane;
        #pragma unroll
        for (int r = 0; r < NR; ++r) vA[r] = xa4[(size_t)r * 64];
        #pragma unroll
        for (int r = 0; r < NR; ++r) vB[r] = xb4[(size_t)r * 64];
    }

    const int rB0 = (((lane >> 5) & 1) << 5) + ((lane & 31) << 6);
    const int wA0 = (lane << 2) ^ (((lane >> 4) & 3) << 2);
    const int l7s = (lane & 7) << 2;

    float4* hv = (float4*)h;
    {
        const float* hp = hadamard + rB0;
        #pragma unroll
        for (int q = 0; q < NR; ++q)
            hv[q] = *reinterpret_cast<const float4*>(hp + (q << 2));
    }

    // Pipeline: each DS batch is covered by the other stream's VALU stage.
    p1a<VAR>(vA); p1b<VAR>(vA, lane);
    wAB(lds, vA, wA0);
    p1a<VAR>(vB);                                  // covers wAB(A)
    LGKM0();
    rAB(lds, vA, rB0, l7s);
    p1b<VAR>(vB, lane);                            // covers rAB(A)
    LGKM0();                                       // vA read done -> buffer free
    wAB(lds, vB, wA0);
    p2<VAR>(vA, lane);
    quant_all(vA, h, s, inv_s, nqn, qp);           // covers wAB(B)
    LGKM0();
    rAB(lds, vB, rB0, l7s);
    p2<VAR>(vA, lane);                             // FWHT2 start on A; covers rAB(B)
    LGKM0();                                       // vB read done -> buffer free
    wBA(lds, vA, rB0, l7s);
    p2<VAR>(vB, lane);
    quant_all(vB, h, s, inv_s, nqn, qp);           // covers wBA(A)
    LGKM0();
    rBA(lds, vA, wA0);
    p2<VAR>(vB, lane);                             // FWHT2 start on B; covers rBA(A)
    LGKM0();                                       // vA read done -> buffer free
    wBA(lds, vB, rB0, l7s);
    p4<VAR>(vA, lane);                             // covers wBA(B)
    LGKM0();
    rBA(lds, vB, wA0);
    {   // store A covers rBA(B)
        f4v* y4 = reinterpret_cast<f4v*>(out + (size_t)rowA * D) + lane;
        #pragma unroll
        for (int r = 0; r < NR; ++r)
            __builtin_nontemporal_store(__builtin_bit_cast(f4v, vA[r]),
                                        &y4[(size_t)r * 64]);
    }
    LGKM0();
    p4<VAR>(vB, lane);
    if (doB) {
        f4v* y4 = reinterpret_cast<f4v*>(out + (size_t)rowB * D) + lane;
        #pragma unroll
        for (int r = 0; r < NR; ++r)
            __builtin_nontemporal_store(__builtin_bit_cast(f4v, vB[r]),
                                        &y4[(size_t)r * 64]);
    }
}

__global__ __launch_bounds__(256) void lsq_fwht_kernel(
    const float* __restrict__ x,
    const float* __restrict__ scale,
    const float* __restrict__ hadamard,
    const int*   __restrict__ qn_p,
    const int*   __restrict__ qp_p,
    const int*   __restrict__ ne_p,
    float*       __restrict__ out,
    int rows)
{
    __shared__ float smem[4][D];              // 8 KiB per wave, wave-private

    const int lane = threadIdx.x & 63;
    const int wave = threadIdx.x >> 6;
    const int rowA = blockIdx.x * 8 + wave * 2;   // two rows per wave
    if (rowA >= rows) return;
    const bool doB = (rowA + 1) < rows;
    const int rowB = doB ? rowA + 1 : rowA;

    float* lds = smem[wave];

    // probe permlane swap semantics once (wave-uniform)
    const int p32v = probe_var<true>(lane);
    const int p16v = probe_var<false>(lane);
    const int var  = (p32v == p16v) ? p32v : 4;

    // LSQ scale trick (forward value == scale), fp32 rounding as in reference
    const float sc    = scale[0];
    const float qp    = (float)qp_p[0];
    const float nqn   = -(float)qn_p[0];
    const float gs    = 1.0f / sqrtf((float)ne_p[0] * qp);
    const float bw    = sc * gs;
    const float s     = (sc - bw) + bw;
    const float inv_s = 1.0f / s;

    switch (var) {
    case 0:  fwht_body<0>(x, hadamard, out, lds, lane, rowA, rowB, doB, s, inv_s, nqn, qp); break;
    case 1:  fwht_body<1>(x, hadamard, out, lds, lane, rowA, rowB, doB, s, inv_s, nqn, qp); break;
    case 2:  fwht_body<2>(x, hadamard, out, lds, lane, rowA, rowB, doB, s, inv_s, nqn, qp); break;
    case 3:  fwht_body<3>(x, hadamard, out, lds, lane, rowA, rowB, doB, s, inv_s, nqn, qp); break;
    default: fwht_body<4>(x, hadamard, out, lds, lane, rowA, rowB, doB, s, inv_s, nqn, qp); break;
    }
}

extern "C" void kernel_launch(void* const* d_in, const int* in_sizes, int n_in,
                              void* d_out, int out_size, void* d_ws, size_t ws_size,
                              hipStream_t stream) {
    const float* x        = (const float*)d_in[0];
    const float* scale    = (const float*)d_in[1];
    const float* hadamard = (const float*)d_in[2];
    const int*   Qn       = (const int*)d_in[3];
    const int*   Qp       = (const int*)d_in[4];
    const int*   ne       = (const int*)d_in[5];
    float*       out      = (float*)d_out;

    const int rows = in_sizes[0] / D;          // 16384 for B=4,S=4096
    const int grid = (rows + 7) / 8;           // 4 waves x 2 rows per block

    lsq_fwht_kernel<<<grid, 256, 0, stream>>>(x, scale, hadamard, Qn, Qp, ne,
                                              out, rows);
}

// Round 6
// 254.234 us; speedup vs baseline: 1.0226x; 1.0226x over previous
//
#include <hip/hip_runtime.h>
#include <math.h>

// LSQ quantizer with Hadamard rotation via FWHT:
//   out_row = FWHT( h0 .* s .* rint(clamp(FWHT(x_row) .* h0 / s, -Qn, Qp)) )
// with h0 = hadamard[0,:] = signs/sqrt(D).
//
// Round-7: revert r6's coupled 2-stream pipeline (regressed). Keep r5's
// straight-line body (2 LDS transposes + compile-time-variant permlane
// butterflies). NEW: persistent waves -- grid = 1024 blocks (4/CU, fully
// resident, zero churn), each wave strides over 4 rows, unrolled x2 with
// role-swapping register sets: next row's 8 global loads are ISSUED at the
// top of the current row's compute (~12k cycles of cover), so the 900-cycle
// row-start load stall disappears. h0 fragment load hoisted out of the loop.
//
// Bit partition of element index j (11 bits):
//   layout A: comps=j[0:2], lanes=j[2:8] (lane bit k = j[k+2]), regs=j[8:11]
//             -> VALU: comps {0,1}, regs {8,9,10}, perm16 = j6, perm32 = j7
//   layout B: comps=j[0:2], regs=j[2:5], lanes: bit5=j5, bits0..4=j[6:11]
//             -> VALU: regs {2,3,4}, perm32 = j5
// LDS swizzle on the linear float address a: a ^= ((a>>6)&7)<<2.
// (measured r3/r4: SQ_LDS_BANK_CONFLICT 8.9M -> 0.52M with this scheme)
// Cross-iteration LDS safety: DS ops from one wave execute in order, so the
// next row's transpose-write cannot pass this row's transpose-read.

constexpr int D  = 2048;
constexpr int NR = 8;   // float4 regs per lane: 8 * 4 * 64 = 2048

#define LGKM0() __asm__ __volatile__("s_waitcnt lgkmcnt(0)" ::: "memory")

typedef unsigned uint2v __attribute__((ext_vector_type(2)));
typedef float    f4v    __attribute__((ext_vector_type(4)));

__device__ __forceinline__ void bfly(float4& a, float4& b) {
    float4 ta = a, tb = b;
    a.x = ta.x + tb.x; a.y = ta.y + tb.y; a.z = ta.z + tb.z; a.w = ta.w + tb.w;
    b.x = ta.x - tb.x; b.y = ta.y - tb.y; b.z = ta.z - tb.z; b.w = ta.w - tb.w;
}

__device__ __forceinline__ void reg_stages(float4 (&v)[NR]) {
    #pragma unroll
    for (int m = 1; m <= 4; m <<= 1) {
        #pragma unroll
        for (int r = 0; r < NR; ++r)
            if ((r & m) == 0) bfly(v[r], v[r | m]);
    }
}

__device__ __forceinline__ void comp_stages(float4 (&v)[NR]) {
    #pragma unroll
    for (int r = 0; r < NR; ++r) {
        float a, b;
        a = v[r].x; b = v[r].y; v[r].x = a + b; v[r].y = a - b;   // bit 0
        a = v[r].z; b = v[r].w; v[r].z = a + b; v[r].w = a - b;
        a = v[r].x; b = v[r].z; v[r].x = a + b; v[r].z = a - b;   // bit 1
        a = v[r].y; b = v[r].w; v[r].y = a + b; v[r].w = a - b;
    }
}

// ---- raw permlane swaps (semantics probed at runtime, once) ----
__device__ __forceinline__ void plswap32(float& x, float& y) {
#if __has_builtin(__builtin_amdgcn_permlane32_swap)
    uint2v t = __builtin_amdgcn_permlane32_swap(
        __builtin_bit_cast(unsigned, x), __builtin_bit_cast(unsigned, y),
        false, false);
    x = __builtin_bit_cast(float, t[0]);
    y = __builtin_bit_cast(float, t[1]);
#else
    asm volatile("v_permlane32_swap_b32 %0, %1" : "+v"(x), "+v"(y));
#endif
}
__device__ __forceinline__ void plswap16(float& x, float& y) {
#if __has_builtin(__builtin_amdgcn_permlane16_swap)
    uint2v t = __builtin_amdgcn_permlane16_swap(
        __builtin_bit_cast(unsigned, x), __builtin_bit_cast(unsigned, y),
        false, false);
    x = __builtin_bit_cast(float, t[0]);
    y = __builtin_bit_cast(float, t[1]);
#else
    asm volatile("v_permlane16_swap_b32 %0, %1" : "+v"(x), "+v"(y));
#endif
}

// Probe: classify swap semantics into variant 0..3 (4 = unknown).
//   0: a <- [a_lo,b_lo], b <- [a_hi,b_hi]   (per m-group pair)
//   1: a <- [a_hi,b_hi], b <- [a_lo,b_lo]
//   2: a <- [b_hi,a_hi], b <- [b_lo,a_lo]
//   3: a <- [b_lo,a_lo], b <- [b_hi,a_hi]
template<bool IS32>
__device__ __forceinline__ int probe_var(int lane) {
    const int m = IS32 ? 32 : 16;
    float a = (float)lane, b = 1000.0f + (float)lane;
    if (IS32) plswap32(a, b); else plswap16(a, b);
    const bool hi = (lane & m) != 0;
    const float ea0 = hi ? 1000.0f + (float)(lane - m) : (float)lane;
    const float eb0 = hi ? 1000.0f + (float)lane       : (float)(lane + m);
    const float ea2 = hi ? (float)lane                 : 1000.0f + (float)(lane + m);
    const float eb2 = hi ? (float)(lane - m)           : 1000.0f + (float)lane;
    if (__all(a == ea0 && b == eb0)) return 0;
    if (__all(a == eb0 && b == ea0)) return 1;
    if (__all(a == ea2 && b == eb2)) return 2;
    if (__all(a == eb2 && b == ea2)) return 3;
    return 4;
}

// Lane butterfly on group-bit m for TWO registers at once, per variant.
// Final a=[sum_a,diff_a], b=[sum_b,diff_b] (diff = lo-hi). Verified per-variant.
template<int VAR, bool IS32>
__device__ __forceinline__ void bfly_l(float& a, float& b) {
    if (IS32) plswap32(a, b); else plswap16(a, b);
    float s = a + b;
    float d = (VAR == 0 || VAR == 3) ? (a - b) : (b - a);
    if (VAR == 0)      { if (IS32) plswap32(s, d); else plswap16(s, d); a = s; b = d; }
    else if (VAR == 1) { if (IS32) plswap32(s, d); else plswap16(s, d); a = d; b = s; }
    else if (VAR == 2) { if (IS32) plswap32(d, s); else plswap16(d, s); a = d; b = s; }
    else               { if (IS32) plswap32(d, s); else plswap16(d, s); a = s; b = d; }
}

// Known-correct fallback: xor-m butterfly via shuffle.
__device__ __forceinline__ void shfl_stage(float4 (&v)[NR], int m, int lane) {
    const bool hi = (lane & m) != 0;
    #pragma unroll
    for (int r = 0; r < NR; ++r) {
        float t;
        t = __shfl_xor(v[r].x, m); v[r].x = hi ? t - v[r].x : v[r].x + t;
        t = __shfl_xor(v[r].y, m); v[r].y = hi ? t - v[r].y : v[r].y + t;
        t = __shfl_xor(v[r].z, m); v[r].z = hi ? t - v[r].z : v[r].z + t;
        t = __shfl_xor(v[r].w, m); v[r].w = hi ? t - v[r].w : v[r].w + t;
    }
}

template<int VAR, bool IS32>
__device__ __forceinline__ void perm_stage(float4 (&v)[NR], int lane) {
    if constexpr (VAR == 4) {
        shfl_stage(v, IS32 ? 32 : 16, lane);
    } else {
        #pragma unroll
        for (int r = 0; r < NR; r += 2) {
            bfly_l<VAR, IS32>(v[r].x, v[r + 1].x);
            bfly_l<VAR, IS32>(v[r].y, v[r + 1].y);
            bfly_l<VAR, IS32>(v[r].z, v[r + 1].z);
            bfly_l<VAR, IS32>(v[r].w, v[r + 1].w);
        }
    }
}

__device__ __forceinline__ float quant1(float xh, float h0, float s, float inv_s,
                                        float nqn, float qp) {
    float u = xh * h0 * inv_s;
    u = fminf(fmaxf(u, nqn), qp);
    float q = rintf(u);                       // round half-to-even (jnp.round)
    return q * (s * h0);                      // *s, fold the second h0 multiply
}

__device__ __forceinline__ void quant_all(float4 (&v)[NR], const float4 (&h)[NR],
                                          float s, float inv_s, float nqn, float qp) {
    #pragma unroll
    for (int r = 0; r < NR; ++r) {
        v[r].x = quant1(v[r].x, h[r].x, s, inv_s, nqn, qp);
        v[r].y = quant1(v[r].y, h[r].y, s, inv_s, nqn, qp);
        v[r].z = quant1(v[r].z, h[r].z, s, inv_s, nqn, qp);
        v[r].w = quant1(v[r].w, h[r].w, s, inv_s, nqn, qp);
    }
}

// ---- LDS transpose batches (8 x b128 each; swizzle a ^= ((a>>6)&7)<<2) ----
__device__ __forceinline__ void wAB(float* lds, const float4 (&v)[NR], int wA0) {
    #pragma unroll
    for (int r = 0; r < NR; ++r)
        *reinterpret_cast<float4*>(lds + (r << 8) + (wA0 ^ ((r & 1) << 4))) = v[r];
}
__device__ __forceinline__ void rAB(float* lds, float4 (&v)[NR], int rB0, int l7s) {
    #pragma unroll
    for (int q = 0; q < NR; ++q)
        v[q] = *reinterpret_cast<const float4*>(lds + rB0 + ((q << 2) ^ l7s));
}
__device__ __forceinline__ void wBA(float* lds, const float4 (&v)[NR], int rB0, int l7s) {
    #pragma unroll
    for (int q = 0; q < NR; ++q)
        *reinterpret_cast<float4*>(lds + rB0 + ((q << 2) ^ l7s)) = v[q];
}
__device__ __forceinline__ void rBA(float* lds, float4 (&v)[NR], int wA0) {
    #pragma unroll
    for (int r = 0; r < NR; ++r)
        v[r] = *reinterpret_cast<const float4*>(lds + (r << 8) + (wA0 ^ ((r & 1) << 4)));
}

// One row: prefetch next row into vN, then full FWHT+quant+FWHT on v, store.
template<int VAR>
__device__ __forceinline__ void row_step(
    const float* __restrict__ x, float* __restrict__ out,
    float* lds, int lane, int row, int nrow, int rows,
    float4 (&v)[NR], float4 (&vN)[NR], const float4 (&h)[NR],
    int rB0, int wA0, int l7s,
    float s, float inv_s, float nqn, float qp)
{
    // ---- prefetch next row (issued now, consumed next step ~12k cyc later)
    if (nrow < rows) {
        const float4* x4 = reinterpret_cast<const float4*>(x + (size_t)nrow * D) + lane;
        #pragma unroll
        for (int r = 0; r < NR; ++r) vN[r] = x4[(size_t)r * 64];
    }

    // ================= FWHT #1 =================
    comp_stages(v);                                   // bits 0,1
    reg_stages(v);                                    // bits 8,9,10
    perm_stage<VAR, false>(v, lane);                  // bit 6 (lane^16)
    perm_stage<VAR, true >(v, lane);                  // bit 7 (lane^32)
    wAB(lds, v, wA0);                                 // transpose A -> B
    LGKM0();
    rAB(lds, v, rB0, l7s);
    reg_stages(v);                                    // bits 2,3,4
    perm_stage<VAR, true >(v, lane);                  // bit 5 (lane^32)

    // ================= quantize (layout B) =================
    quant_all(v, h, s, inv_s, nqn, qp);

    // ================= FWHT #2 =================
    reg_stages(v);                                    // bits 2,3,4
    perm_stage<VAR, true >(v, lane);                  // bit 5
    wBA(lds, v, rB0, l7s);                            // transpose B -> A
    LGKM0();
    rBA(lds, v, wA0);
    reg_stages(v);                                    // bits 8,9,10
    perm_stage<VAR, false>(v, lane);                  // bit 6
    perm_stage<VAR, true >(v, lane);                  // bit 7
    comp_stages(v);                                   // bits 0,1

    // ---- store (layout A, coalesced, nontemporal) ----
    f4v* y4 = reinterpret_cast<f4v*>(out + (size_t)row * D) + lane;
    #pragma unroll
    for (int r = 0; r < NR; ++r)
        __builtin_nontemporal_store(__builtin_bit_cast(f4v, v[r]),
                                    &y4[(size_t)r * 64]);
}

// Persistent wave: strides over rows, x2 unrolled with role-swapped reg sets.
template<int VAR>
__device__ __forceinline__ void fwht_body(
    const float* __restrict__ x, const float* __restrict__ hadamard,
    float* __restrict__ out, float* lds, int lane, int gwave, int nwaves,
    int rows, float s, float inv_s, float nqn, float qp)
{
    const int rB0 = (((lane >> 5) & 1) << 5) + ((lane & 31) << 6);
    const int wA0 = (lane << 2) ^ (((lane >> 4) & 3) << 2);
    const int l7s = (lane & 7) << 2;

    // h0 in layout B -- row-invariant, loaded once per wave
    float4 h[NR];
    {
        const float* hp = hadamard + rB0;
        #pragma unroll
        for (int q = 0; q < NR; ++q)
            h[q] = *reinterpret_cast<const float4*>(hp + (q << 2));
    }

    float4 vA[NR], vB[NR];
    int row = gwave;
    {
        const float4* x4 = reinterpret_cast<const float4*>(x + (size_t)row * D) + lane;
        #pragma unroll
        for (int r = 0; r < NR; ++r) vA[r] = x4[(size_t)r * 64];
    }

    for (;;) {
        int nrow = row + nwaves;
        row_step<VAR>(x, out, lds, lane, row, nrow, rows, vA, vB, h,
                      rB0, wA0, l7s, s, inv_s, nqn, qp);
        if (nrow >= rows) break;
        row = nrow; nrow = row + nwaves;
        row_step<VAR>(x, out, lds, lane, row, nrow, rows, vB, vA, h,
                      rB0, wA0, l7s, s, inv_s, nqn, qp);
        if (nrow >= rows) break;
        row = nrow;
    }
}

__global__ __launch_bounds__(256) void lsq_fwht_kernel(
    const float* __restrict__ x,
    const float* __restrict__ scale,
    const float* __restrict__ hadamard,
    const int*   __restrict__ qn_p,
    const int*   __restrict__ qp_p,
    const int*   __restrict__ ne_p,
    float*       __restrict__ out,
    int rows)
{
    __shared__ float smem[4][D];              // 8 KiB per wave, wave-private

    const int lane   = threadIdx.x & 63;
    const int wave   = threadIdx.x >> 6;
    const int gwave  = blockIdx.x * 4 + wave;
    const int nwaves = gridDim.x * 4;
    if (gwave >= rows) return;

    float* lds = smem[wave];

    // probe permlane swap semantics once (wave-uniform)
    const int p32v = probe_var<true>(lane);
    const int p16v = probe_var<false>(lane);
    const int var  = (p32v == p16v) ? p32v : 4;

    // LSQ scale trick (forward value == scale), fp32 rounding as in reference
    const float sc    = scale[0];
    const float qp    = (float)qp_p[0];
    const float nqn   = -(float)qn_p[0];
    const float gs    = 1.0f / sqrtf((float)ne_p[0] * qp);
    const float bw    = sc * gs;
    const float s     = (sc - bw) + bw;
    const float inv_s = 1.0f / s;

    switch (var) {
    case 0:  fwht_body<0>(x, hadamard, out, lds, lane, gwave, nwaves, rows, s, inv_s, nqn, qp); break;
    case 1:  fwht_body<1>(x, hadamard, out, lds, lane, gwave, nwaves, rows, s, inv_s, nqn, qp); break;
    case 2:  fwht_body<2>(x, hadamard, out, lds, lane, gwave, nwaves, rows, s, inv_s, nqn, qp); break;
    case 3:  fwht_body<3>(x, hadamard, out, lds, lane, gwave, nwaves, rows, s, inv_s, nqn, qp); break;
    default: fwht_body<4>(x, hadamard, out, lds, lane, gwave, nwaves, rows, s, inv_s, nqn, qp); break;
    }
}

extern "C" void kernel_launch(void* const* d_in, const int* in_sizes, int n_in,
                              void* d_out, int out_size, void* d_ws, size_t ws_size,
                              hipStream_t stream) {
    const float* x        = (const float*)d_in[0];
    const float* scale    = (const float*)d_in[1];
    const float* hadamard = (const float*)d_in[2];
    const int*   Qn       = (const int*)d_in[3];
    const int*   Qp       = (const int*)d_in[4];
    const int*   ne       = (const int*)d_in[5];
    float*       out      = (float*)d_out;

    const int rows = in_sizes[0] / D;          // 16384 for B=4,S=4096
    // Persistent-ish grid: 1024 blocks = 4 blocks/CU (128 KiB LDS/CU),
    // fully resident, each wave strides over rows (4 rows/wave at 16384).
    int grid = (rows + 3) / 4;
    if (grid > 1024) grid = 1024;

    lsq_fwht_kernel<<<grid, 256, 0, stream>>>(x, scale, hadamard, Qn, Qp, ne,
                                              out, rows);
}